// Round 8
// baseline (38.133 us; speedup 1.0000x reference)
//
#include <hip/hip_runtime.h>
#include <math.h>

#define HIDDEN 2048
#define IN_F 350
#define NBLK 512
#define NTHR 768

// ws layout (bytes):
//   [0      .. 8192)   h1  (2048 floats, relaxed agent-scope)
//   [8192   .. 16384)  h2  (2048 floats)
//   [32768  .. 33792)  cnt1: 8 counter lines, 128 B apart (h1-done)
//   [33792  .. 34816)  cnt2: 8 counter lines (h2-done)
// cnt region (2 KB) memset to 0 every call.

__device__ __forceinline__ float sigmoidf_(float v) { return 1.0f / (1.0f + expf(-v)); }
__device__ __forceinline__ float dot4_(float4 a, float4 b) {
    return a.x*b.x + a.y*b.y + a.z*b.z + a.w*b.w;
}

// Single fused kernel: all HBM loads issued at t0; compute overlaps the stream.
// 512 blocks x 768 thr (12 waves) = exactly 2 blocks/CU -> all co-resident
// (launch_bounds(,6) guarantees 6 waves/SIMD => 2 blocks/CU; pigeonhole => no
// pending blocks => spinning on counters cannot deadlock).
// h=c=0 for both LSTM cells => f-gates dead, W_hh unused.
__global__ __launch_bounds__(NTHR, 6) void fused_all(
    const float* __restrict__ x,
    const float* __restrict__ Wih0, const float* __restrict__ bih0, const float* __restrict__ bhh0,
    const float* __restrict__ Wih1, const float* __restrict__ bih1, const float* __restrict__ bhh1,
    const float* __restrict__ fcw,  const float* __restrict__ fcb,
    float* __restrict__ h1g, float* __restrict__ h2g,
    unsigned* __restrict__ cnt1, unsigned* __restrict__ cnt2,
    float* __restrict__ out)
{
    __shared__ __align__(16) float feat[IN_F + 2];
    __shared__ __align__(16) float h1s[HIDDEN];     // reused for h2 in fc phase
    __shared__ float hxs[84], scs[12], exts[4], gd[12], part[8];

    const int tid = threadIdx.x, wave = tid >> 6, lane = tid & 63;
    const int b = blockIdx.x;

    // ================= t0: issue ALL global loads, in consumption order ======
    // (1) x pieces (waves 0-2 only; earliest-consumed)
    float hxv = 0.f, scv = 0.f, vx = 0.f, vy = 0.f;
    if (tid < 84) hxv = x[182 + tid];                       // hand coords
    if (tid >= 96 && tid < 104) {                           // 4 source points
        int t = tid - 96, p = t >> 1;
        int base = (p == 0) ? 0 : (p == 1) ? 106 : (p == 2) ? 200 : 242;
        scv = x[base + (t & 1)];
    }
    if (tid < 133) { vx = x[2*tid]; vy = x[2*tid + 1]; }

    // (2) layer-0 weight row + both layers' biases
    const int u  = b * 4 + wave / 3;                        // hidden unit
    const int g3 = wave % 3;                                // 0,1,2 -> gates i,g,o
    const int grow = ((g3 == 0) ? 0 : (g3 == 1) ? 2 : 3) * HIDDEN + u;
    const float2* w0r = (const float2*)(Wih0 + (size_t)grow * IN_F);
    const bool has2 = (128 + lane) < 175;                   // 350 floats = 175 float2
    float2 a0 = w0r[lane];
    float2 a1 = w0r[64 + lane];
    float2 a2 = has2 ? w0r[128 + lane] : make_float2(0.f, 0.f);
    float bsum0 = bih0[grow] + bhh0[grow];
    float bsum1 = bih1[grow] + bhh1[grow];

    // (3) layer-1 weight prefetch: 8 x float4/lane, held in regs across phase A
    const float4* w1r = (const float4*)(Wih1 + (size_t)grow * HIDDEN);
    float4 wv0 = w1r[lane],       wv1 = w1r[ 64 + lane];
    float4 wv2 = w1r[128 + lane], wv3 = w1r[192 + lane];
    float4 wv4 = w1r[256 + lane], wv5 = w1r[320 + lane];
    float4 wv6 = w1r[384 + lane], wv7 = w1r[448 + lane];

    // (4) fc row prefetch (blocks < IN_F own output row b)
    float4 fcv = make_float4(0.f, 0.f, 0.f, 0.f);
    float fcbv = 0.f;
    if (b < IN_F && tid < 512) fcv = ((const float4*)(fcw + (size_t)b * HIDDEN))[tid];
    if (b < IN_F && tid == 0)  fcbv = fcb[b];

    // ================= phase A: feat + LSTM layer 0 ===========================
    if (tid < 84) hxs[tid] = hxv;
    if (tid >= 96 && tid < 104) scs[tid - 96] = scv;
    __syncthreads();
    if (tid < 4) {                                          // hand extrema
        int h = tid >> 1, c = tid & 1;
        float m = hxs[h*42 + c], M = m;
        #pragma unroll
        for (int j = 1; j < 21; ++j) {
            float v = hxs[h*42 + 2*j + c];
            m = fminf(m, v); M = fmaxf(M, v);
        }
        exts[tid] = M - m;
    }
    __syncthreads();
    if (tid < 4) {
        int h = tid >> 1;
        bool ok = (exts[2*h] != 0.f) && (exts[2*h + 1] != 0.f);
        scs[8 + tid] = ok ? exts[tid] : 1.f;
    }
    __syncthreads();
    if (tid < 133) {
        const float sbx = scs[0], sby = scs[1], sfx = scs[2], sfy = scs[3];
        const float slx = scs[4], sly = scs[5], srx = scs[6], sry = scs[7];
        const float dlx = scs[8], dly = scs[9], drx = scs[10], dry = scs[11];
        const int k = tid;
        if (k < 17) {                 // body
            feat[2*k]   = vx - sbx;  feat[2*k+1] = vy - sby;
        } else if (k < 23) {          // feet
            feat[2*k]   = vx;        feat[2*k+1] = vy;
        } else if (k < 91) {          // face
            feat[2*k]   = vx - sfx;  feat[2*k+1] = vy - sfy;
        } else if (k < 112) {         // left hand + chin2l
            int jj = k - 91;
            feat[182 + 2*jj] = (vx - slx) / dlx;  feat[183 + 2*jj] = (vy - sly) / dly;
            feat[266 + 2*jj] = vx - sbx;          feat[267 + 2*jj] = vy - sby;
        } else {                      // right hand + chin2r
            int jj = k - 112;
            feat[224 + 2*jj] = (vx - srx) / drx;  feat[225 + 2*jj] = (vy - sry) / dry;
            feat[308 + 2*jj] = vx - sbx;          feat[309 + 2*jj] = vy - sby;
        }
    }
    __syncthreads();
    {   // layer-0 gate dot (K=350)
        const float2* f2 = (const float2*)feat;
        float2 f0 = f2[lane], f1 = f2[64 + lane];
        float2 fx = has2 ? f2[128 + lane] : make_float2(0.f, 0.f);
        float acc = a0.x*f0.x + a0.y*f0.y + a1.x*f1.x + a1.y*f1.y + a2.x*fx.x + a2.y*fx.y;
        #pragma unroll
        for (int off = 32; off; off >>= 1) acc += __shfl_down(acc, off);
        if (lane == 0) gd[wave] = acc + bsum0;
    }
    __syncthreads();
    if (tid < 4) {
        float c = sigmoidf_(gd[3*tid]) * tanhf(gd[3*tid + 1]);
        float h = sigmoidf_(gd[3*tid + 2]) * tanhf(c);
        __hip_atomic_store(&h1g[b*4 + tid], h, __ATOMIC_RELAXED, __HIP_MEMORY_SCOPE_AGENT);
    }
    if (tid == 0) {
        asm volatile("s_waitcnt vmcnt(0)" ::: "memory");    // wave-0 h1 stores at LLC
        __hip_atomic_fetch_add(&cnt1[(b & 7) * 32], 1u,
                               __ATOMIC_RELAXED, __HIP_MEMORY_SCOPE_AGENT);
        for (;;) {                                          // spin: 8 spread lines
            unsigned s = 0;
            #pragma unroll
            for (int i = 0; i < 8; ++i)
                s += __hip_atomic_load(&cnt1[i * 32], __ATOMIC_RELAXED,
                                       __HIP_MEMORY_SCOPE_AGENT);
            if (s >= (unsigned)NBLK) break;
            __builtin_amdgcn_s_sleep(8);
        }
    }
    __syncthreads();

    // ================= phase B: LSTM layer 1 (weights already in regs) =======
    for (int i = tid; i < HIDDEN; i += NTHR)
        h1s[i] = __hip_atomic_load(&h1g[i], __ATOMIC_RELAXED, __HIP_MEMORY_SCOPE_AGENT);
    __syncthreads();
    {
        const float4* h4 = (const float4*)h1s;
        float acc = dot4_(wv0, h4[lane])       + dot4_(wv1, h4[ 64 + lane])
                  + dot4_(wv2, h4[128 + lane]) + dot4_(wv3, h4[192 + lane])
                  + dot4_(wv4, h4[256 + lane]) + dot4_(wv5, h4[320 + lane])
                  + dot4_(wv6, h4[384 + lane]) + dot4_(wv7, h4[448 + lane]);
        #pragma unroll
        for (int off = 32; off; off >>= 1) acc += __shfl_down(acc, off);
        if (lane == 0) gd[wave] = acc + bsum1;
    }
    __syncthreads();
    if (tid < 4) {
        float c = sigmoidf_(gd[3*tid]) * tanhf(gd[3*tid + 1]);
        float h = sigmoidf_(gd[3*tid + 2]) * tanhf(c);
        __hip_atomic_store(&h2g[b*4 + tid], h, __ATOMIC_RELAXED, __HIP_MEMORY_SCOPE_AGENT);
    }
    if (tid == 0) {
        asm volatile("s_waitcnt vmcnt(0)" ::: "memory");
        __hip_atomic_fetch_add(&cnt2[(b & 7) * 32], 1u,
                               __ATOMIC_RELAXED, __HIP_MEMORY_SCOPE_AGENT);
    }
    if (b >= IN_F) return;                                  // uniform per block

    // ================= phase C: fc row b (weights already in regs) ===========
    if (tid == 0) {
        for (;;) {
            unsigned s = 0;
            #pragma unroll
            for (int i = 0; i < 8; ++i)
                s += __hip_atomic_load(&cnt2[i * 32], __ATOMIC_RELAXED,
                                       __HIP_MEMORY_SCOPE_AGENT);
            if (s >= (unsigned)NBLK) break;
            __builtin_amdgcn_s_sleep(8);
        }
    }
    __syncthreads();
    for (int i = tid; i < HIDDEN; i += NTHR)                // reuse h1s for h2
        h1s[i] = __hip_atomic_load(&h2g[i], __ATOMIC_RELAXED, __HIP_MEMORY_SCOPE_AGENT);
    __syncthreads();
    {
        float p = 0.f;
        if (tid < 512) p = dot4_(fcv, ((const float4*)h1s)[tid]);
        #pragma unroll
        for (int off = 32; off; off >>= 1) p += __shfl_down(p, off);
        if (lane == 0 && wave < 8) part[wave] = p;
    }
    __syncthreads();
    if (tid == 0) {
        out[b] = part[0] + part[1] + part[2] + part[3]
               + part[4] + part[5] + part[6] + part[7] + fcbv;
    }
}

extern "C" void kernel_launch(void* const* d_in, const int* in_sizes, int n_in,
                              void* d_out, int out_size, void* d_ws, size_t ws_size,
                              hipStream_t stream) {
    const float* x     = (const float*)d_in[0];
    const float* W_ih0 = (const float*)d_in[1];
    // d_in[2] = W_hh0 : unused (h0 == 0)
    const float* b_ih0 = (const float*)d_in[3];
    const float* b_hh0 = (const float*)d_in[4];
    const float* W_ih1 = (const float*)d_in[5];
    // d_in[6] = W_hh1 : unused (h == 0 for cell 2 as well)
    const float* b_ih1 = (const float*)d_in[7];
    const float* b_hh1 = (const float*)d_in[8];
    const float* fc_w  = (const float*)d_in[9];
    const float* fc_b  = (const float*)d_in[10];

    float*    h1g  = (float*)d_ws;                         // 2048 floats
    float*    h2g  = (float*)d_ws + HIDDEN;                // 2048 floats
    unsigned* cnt1 = (unsigned*)((char*)d_ws + 32768);     // 8 lines x 128 B
    unsigned* cnt2 = (unsigned*)((char*)d_ws + 33792);     // 8 lines x 128 B

    hipMemsetAsync((char*)d_ws + 32768, 0, 2048, stream);  // re-arm counters
    fused_all<<<NBLK, NTHR, 0, stream>>>(
        x, W_ih0, b_ih0, b_hh0, W_ih1, b_ih1, b_hh1, fc_w, fc_b,
        h1g, h2g, cnt1, cnt2, (float*)d_out);
}

// Round 9
// 27.525 us; speedup vs baseline: 1.3854x; 1.3854x over previous
//
#include <hip/hip_runtime.h>
#include <math.h>

#define HIDDEN 2048
#define IN_F 350

__device__ __forceinline__ float sigmoidf_(float v) { return 1.0f / (1.0f + expf(-v)); }
__device__ __forceinline__ float dot4_(float4 a, float4 b) {
    return a.x*b.x + a.y*b.y + a.z*b.z + a.w*b.w;
}

// K1: feat + LSTM layer 0 (h=c=0 => f-gate dead, W_hh unused)
//     + L3-warm prefetch of W_ih1 (live gates i,g,o) and fc_w.
// 512 blocks x 768 thr (12 waves). Block b owns units [4b,4b+4);
// wave w -> (unit 4b + w/3, gate w%3).
// Prefetch: 512*768 = 393216 threads == 3 live gate regions x 131072 lines
// (128 B each) of W_ih1; threads < 22400 also touch fc_w's 22400 lines.
// One dword per line pulls the full line into L2/L3; k2/k3 then hit cache.
__global__ __launch_bounds__(768) void k1_feat_lstm0(
    const float* __restrict__ x, const float* __restrict__ Wih,
    const float* __restrict__ bih, const float* __restrict__ bhh,
    const float* __restrict__ Wih1, const float* __restrict__ fcw,
    float* __restrict__ h1)
{
    __shared__ __align__(16) float feat[IN_F];
    __shared__ float hx[84];     // hands, contiguous copy of x[182..265]
    __shared__ float sc[12];     // 4 source points (8) + dl/dr (4)
    __shared__ float ext[4];     // wl, hl, wr, hr
    __shared__ float gd[12];
    const int tid = threadIdx.x, wave = tid >> 6, lane = tid & 63;
    const int b = blockIdx.x;

    // ---- L3-warm prefetch (issued first; sunk at the end; no sync needed) ----
    const size_t gtid = (size_t)b * 768 + tid;               // 0 .. 393215
    const int    preg = (int)(gtid >> 17);                   // region 0,1,2
    const size_t poff = (gtid & 131071) * 32;                // line*32 floats
    const size_t rbase = (preg == 0) ? 0 : (size_t)(preg + 1) * HIDDEN * HIDDEN; // i,g,o
    float pf0 = Wih1[rbase + poff];
    float pf1 = (gtid < 22400) ? fcw[gtid * 32] : 0.0f;      // 350*2048 floats

    if (tid < 84) hx[tid] = x[182 + tid];
    else if (tid >= 128 && tid < 136) {
        int t = tid - 128;
        int p = t >> 1;                                      // body,face,left,right
        int base = (p == 0) ? 0 : (p == 1) ? 106 : (p == 2) ? 200 : 242;
        sc[t] = x[base + (t & 1)];
    }
    __syncthreads();
    if (tid < 4) {                                           // extrema: (hand, coord)
        const int h = tid >> 1, c = tid & 1;
        float m = hx[h*42 + c], M = m;
        #pragma unroll
        for (int jj = 1; jj < 21; ++jj) {
            float v = hx[h*42 + 2*jj + c];
            m = fminf(m, v); M = fmaxf(M, v);
        }
        ext[tid] = M - m;
    }
    __syncthreads();
    if (tid < 4) {
        const int h = tid >> 1;
        bool ok = (ext[2*h] != 0.0f) && (ext[2*h + 1] != 0.0f);
        sc[8 + tid] = ok ? ext[tid] : 1.0f;
    }
    __syncthreads();
    if (tid < 133) {
        const float sbx = sc[0], sby = sc[1], sfx = sc[2], sfy = sc[3];
        const float slx = sc[4], sly = sc[5], srx = sc[6], sry = sc[7];
        const float dlx = sc[8], dly = sc[9], drx = sc[10], dry = sc[11];
        const int k = tid;
        float vx = x[2*k], vy = x[2*k + 1];
        if (k < 17) {                 // body
            feat[2*k]   = vx - sbx;  feat[2*k+1] = vy - sby;
        } else if (k < 23) {          // feet
            feat[2*k]   = vx;        feat[2*k+1] = vy;
        } else if (k < 91) {          // face
            feat[2*k]   = vx - sfx;  feat[2*k+1] = vy - sfy;
        } else if (k < 112) {         // left hand + chin2l
            int jj = k - 91;
            feat[182 + 2*jj] = (vx - slx) / dlx;  feat[183 + 2*jj] = (vy - sly) / dly;
            feat[266 + 2*jj] = vx - sbx;          feat[267 + 2*jj] = vy - sby;
        } else {                      // right hand + chin2r
            int jj = k - 112;
            feat[224 + 2*jj] = (vx - srx) / drx;  feat[225 + 2*jj] = (vy - sry) / dry;
            feat[308 + 2*jj] = vx - sbx;          feat[309 + 2*jj] = vy - sby;
        }
    }
    __syncthreads();

    // wave w: unit u = 4b + w/3, gate = w%3 -> row {0,2,3}[gate]*H + u
    const int u = b * 4 + wave / 3;
    const int gate = wave % 3;
    const int grow = ((gate == 0) ? 0 : (gate == 1) ? 2 : 3) * HIDDEN + u;
    const float2* wr = (const float2*)(Wih + (size_t)grow * IN_F);
    const float2* f2 = (const float2*)feat;
    const bool has2 = (128 + lane) < 175;
    float2 w0 = wr[lane];
    float2 w1 = wr[64 + lane];
    float2 w2 = has2 ? wr[128 + lane] : make_float2(0.f, 0.f);
    float2 f0 = f2[lane];
    float2 f1 = f2[64 + lane];
    float2 fx = has2 ? f2[128 + lane] : make_float2(0.f, 0.f);
    float acc = w0.x*f0.x + w0.y*f0.y + w1.x*f1.x + w1.y*f1.y + w2.x*fx.x + w2.y*fx.y;
    #pragma unroll
    for (int off = 32; off; off >>= 1) acc += __shfl_down(acc, off);
    if (lane == 0) gd[wave] = acc + bih[grow] + bhh[grow];
    __syncthreads();
    if (tid < 4) {
        float c = sigmoidf_(gd[3*tid + 0]) * tanhf(gd[3*tid + 1]);
        h1[b*4 + tid] = sigmoidf_(gd[3*tid + 2]) * tanhf(c);
    }

    // keep prefetch loads alive (no-op sink; rule: ablation-via-skip DCE)
    asm volatile("" :: "v"(pf0), "v"(pf1));
}

// K2: LSTM layer 1 (h=c=0 again). 512 blocks x 768 thr (12 waves = 4 units x
// 3 gates, 2 blocks/CU = 24 waves/CU). h1 staged in LDS; weight rows 8 x
// float4/lane, all hoisted. Weights should be L3-warm from K1's prefetch.
__global__ __launch_bounds__(768) void k2_lstm1(
    const float* __restrict__ Wih, const float* __restrict__ bih,
    const float* __restrict__ bhh, const float* __restrict__ h1,
    float* __restrict__ h2)
{
    __shared__ __align__(16) float h1s[HIDDEN];
    __shared__ float gd[12];
    const int tid = threadIdx.x, wave = tid >> 6, lane = tid & 63;
    const int b = blockIdx.x;

    {   // stage h1: 512 float4 over 768 threads
        const float4* h4g = (const float4*)h1;
        float4* h4s = (float4*)h1s;
        if (tid < 512) h4s[tid] = h4g[tid];
    }
    __syncthreads();

    const int u = b * 4 + wave / 3;
    const int gate = wave % 3;
    const int grow = ((gate == 0) ? 0 : (gate == 1) ? 2 : 3) * HIDDEN + u;
    const float4* wr = (const float4*)(Wih + (size_t)grow * HIDDEN);
    const float4* h4 = (const float4*)h1s;

    float4 wv0 = wr[lane];
    float4 wv1 = wr[ 64 + lane];
    float4 wv2 = wr[128 + lane];
    float4 wv3 = wr[192 + lane];
    float4 wv4 = wr[256 + lane];
    float4 wv5 = wr[320 + lane];
    float4 wv6 = wr[384 + lane];
    float4 wv7 = wr[448 + lane];

    float acc = dot4_(wv0, h4[lane])       + dot4_(wv1, h4[ 64 + lane])
              + dot4_(wv2, h4[128 + lane]) + dot4_(wv3, h4[192 + lane])
              + dot4_(wv4, h4[256 + lane]) + dot4_(wv5, h4[320 + lane])
              + dot4_(wv6, h4[384 + lane]) + dot4_(wv7, h4[448 + lane]);
    #pragma unroll
    for (int off = 32; off; off >>= 1) acc += __shfl_down(acc, off);
    if (lane == 0) gd[wave] = acc + bih[grow] + bhh[grow];
    __syncthreads();
    if (tid < 4) {
        float c = sigmoidf_(gd[3*tid + 0]) * tanhf(gd[3*tid + 1]);
        h2[b*4 + tid] = sigmoidf_(gd[3*tid + 2]) * tanhf(c);
    }
}

// K3: out[r] = fc_w[r,:] . h2 + fc_b[r]. 350 blocks x 256 thr (4 waves,
// K-split). fc_w is L3-warm from K1.
__global__ __launch_bounds__(256) void k3_fc(
    const float* __restrict__ h2, const float* __restrict__ W,
    const float* __restrict__ b, float* __restrict__ out)
{
    __shared__ float part[4];
    const int tid = threadIdx.x, wave = tid >> 6, lane = tid & 63;
    const int r = blockIdx.x;
    const float4* wr = (const float4*)(W + (size_t)r * HIDDEN);
    const float4* h4 = (const float4*)h2;
    const int base = wave * 128;              // 512 float4 / 4 waves
    float4 w0 = wr[base + lane], w1 = wr[base + 64 + lane];
    float4 v0 = h4[base + lane], v1 = h4[base + 64 + lane];
    float acc = dot4_(w0, v0) + dot4_(w1, v1);
    #pragma unroll
    for (int off = 32; off; off >>= 1) acc += __shfl_down(acc, off);
    if (lane == 0) part[wave] = acc;
    __syncthreads();
    if (tid == 0) out[r] = part[0] + part[1] + part[2] + part[3] + b[r];
}

extern "C" void kernel_launch(void* const* d_in, const int* in_sizes, int n_in,
                              void* d_out, int out_size, void* d_ws, size_t ws_size,
                              hipStream_t stream) {
    const float* x     = (const float*)d_in[0];
    const float* W_ih0 = (const float*)d_in[1];
    // d_in[2] = W_hh0 : unused (h0 == 0)
    const float* b_ih0 = (const float*)d_in[3];
    const float* b_hh0 = (const float*)d_in[4];
    const float* W_ih1 = (const float*)d_in[5];
    // d_in[6] = W_hh1 : unused (h == 0 for cell 2 as well)
    const float* b_ih1 = (const float*)d_in[7];
    const float* b_hh1 = (const float*)d_in[8];
    const float* fc_w  = (const float*)d_in[9];
    const float* fc_b  = (const float*)d_in[10];

    float* h1 = (float*)d_ws;            // 2048 floats
    float* h2 = (float*)d_ws + HIDDEN;   // 2048 floats

    k1_feat_lstm0<<<512, 768, 0, stream>>>(x, W_ih0, b_ih0, b_hh0,
                                           W_ih1, fc_w, h1);
    k2_lstm1<<<512, 768, 0, stream>>>(W_ih1, b_ih1, b_hh1, h1, h2);
    k3_fc<<<IN_F, 256, 0, stream>>>(h2, fc_w, fc_b, (float*)d_out);
}

// Round 10
// 25.617 us; speedup vs baseline: 1.4886x; 1.0745x over previous
//
#include <hip/hip_runtime.h>
#include <math.h>

#define HIDDEN 2048
#define IN_F 350

// ws layout (floats): [0..2048) h1; [2048..8192) gates (i:0-2047, g:2048-4095,
// o:4096-6143 — bias already added by k2). h2 never materialized globally.

__device__ __forceinline__ float sigmoidf_(float v) { return 1.0f / (1.0f + expf(-v)); }
__device__ __forceinline__ float dot4_(float4 a, float4 b) {
    return a.x*b.x + a.y*b.y + a.z*b.z + a.w*b.w;
}

// K1: feat + LSTM layer 0 (h=c=0 => f-gate dead, W_hh unused).
// 512 blocks x 768 thr (12 waves). Block b owns units [4b,4b+4);
// wave w -> (unit 4b + w/3, gate w%3). feat computed per block, parallel.
__global__ __launch_bounds__(768) void k1_feat_lstm0(
    const float* __restrict__ x, const float* __restrict__ Wih,
    const float* __restrict__ bih, const float* __restrict__ bhh,
    float* __restrict__ h1)
{
    __shared__ __align__(16) float feat[IN_F];
    __shared__ float hx[84];     // hands, contiguous copy of x[182..265]
    __shared__ float sc[12];     // 4 source points (8) + dl/dr (4)
    __shared__ float ext[4];     // wl, hl, wr, hr
    __shared__ float gd[12];
    const int tid = threadIdx.x, wave = tid >> 6, lane = tid & 63;
    const int b = blockIdx.x;

    if (tid < 84) hx[tid] = x[182 + tid];
    else if (tid >= 128 && tid < 136) {
        int t = tid - 128;
        int p = t >> 1;                                   // body,face,left,right
        int base = (p == 0) ? 0 : (p == 1) ? 106 : (p == 2) ? 200 : 242;
        sc[t] = x[base + (t & 1)];
    }
    __syncthreads();
    if (tid < 4) {                                        // extrema: (hand, coord)
        const int h = tid >> 1, c = tid & 1;
        float m = hx[h*42 + c], M = m;
        #pragma unroll
        for (int jj = 1; jj < 21; ++jj) {
            float v = hx[h*42 + 2*jj + c];
            m = fminf(m, v); M = fmaxf(M, v);
        }
        ext[tid] = M - m;
    }
    __syncthreads();
    if (tid < 4) {
        const int h = tid >> 1;
        bool ok = (ext[2*h] != 0.0f) && (ext[2*h + 1] != 0.0f);
        sc[8 + tid] = ok ? ext[tid] : 1.0f;
    }
    __syncthreads();
    if (tid < 133) {
        const float sbx = sc[0], sby = sc[1], sfx = sc[2], sfy = sc[3];
        const float slx = sc[4], sly = sc[5], srx = sc[6], sry = sc[7];
        const float dlx = sc[8], dly = sc[9], drx = sc[10], dry = sc[11];
        const int k = tid;
        float vx = x[2*k], vy = x[2*k + 1];
        if (k < 17) {                 // body
            feat[2*k]   = vx - sbx;  feat[2*k+1] = vy - sby;
        } else if (k < 23) {          // feet
            feat[2*k]   = vx;        feat[2*k+1] = vy;
        } else if (k < 91) {          // face
            feat[2*k]   = vx - sfx;  feat[2*k+1] = vy - sfy;
        } else if (k < 112) {         // left hand + chin2l
            int jj = k - 91;
            feat[182 + 2*jj] = (vx - slx) / dlx;  feat[183 + 2*jj] = (vy - sly) / dly;
            feat[266 + 2*jj] = vx - sbx;          feat[267 + 2*jj] = vy - sby;
        } else {                      // right hand + chin2r
            int jj = k - 112;
            feat[224 + 2*jj] = (vx - srx) / drx;  feat[225 + 2*jj] = (vy - sry) / dry;
            feat[308 + 2*jj] = vx - sbx;          feat[309 + 2*jj] = vy - sby;
        }
    }
    __syncthreads();

    // wave w: unit u = 4b + w/3, gate = w%3 -> row {0,2,3}[gate]*H + u
    const int u = b * 4 + wave / 3;
    const int gate = wave % 3;
    const int grow = ((gate == 0) ? 0 : (gate == 1) ? 2 : 3) * HIDDEN + u;
    const float2* wr = (const float2*)(Wih + (size_t)grow * IN_F);
    const float2* f2 = (const float2*)feat;
    const bool has2 = (128 + lane) < 175;
    float2 w0 = wr[lane];
    float2 w1 = wr[64 + lane];
    float2 w2 = has2 ? wr[128 + lane] : make_float2(0.f, 0.f);
    float2 f0 = f2[lane];
    float2 f1 = f2[64 + lane];
    float2 fx = has2 ? f2[128 + lane] : make_float2(0.f, 0.f);
    float acc = w0.x*f0.x + w0.y*f0.y + w1.x*f1.x + w1.y*f1.y + w2.x*fx.x + w2.y*fx.y;
    #pragma unroll
    for (int off = 32; off; off >>= 1) acc += __shfl_down(acc, off);
    if (lane == 0) gd[wave] = acc + bih[grow] + bhh[grow];
    __syncthreads();
    if (tid < 4) {
        float c = sigmoidf_(gd[3*tid + 0]) * tanhf(gd[3*tid + 1]);
        h1[b*4 + tid] = sigmoidf_(gd[3*tid + 2]) * tanhf(c);
    }
}

// K2: pure row-streaming gate dots for layer 1. 1536 blocks x 256 thr
// (4 waves, no LDS, no syncthreads -> up to 32 waves/CU).
// Wave owns one live gate-row (6144 total: i/g/o x 2048 units), K=2048.
// 8 hoisted float4 weight loads; h1 read via L1 (8 KB, resident after warmup).
// Writes bias-added gate scalar to ws; activations deferred to K3.
__global__ __launch_bounds__(256) void k2_rows(
    const float* __restrict__ Wih, const float* __restrict__ bih,
    const float* __restrict__ bhh, const float* __restrict__ h1,
    float* __restrict__ gates)
{
    const int wave = threadIdx.x >> 6, lane = threadIdx.x & 63;
    const int row = blockIdx.x * 4 + wave;        // 0..6143, gate region = row>>11
    const int g = row >> 11;                      // 0,1,2 -> i,g,o
    const int j = row & (HIDDEN - 1);
    const int grow = ((g == 0) ? 0 : (g == 1) ? 2 : 3) * HIDDEN + j;
    const float4* wr = (const float4*)(Wih + (size_t)grow * HIDDEN);
    const float4* h4 = (const float4*)h1;

    float4 w0 = wr[lane],       w1 = wr[ 64 + lane];
    float4 w2 = wr[128 + lane], w3 = wr[192 + lane];
    float4 w4 = wr[256 + lane], w5 = wr[320 + lane];
    float4 w6 = wr[384 + lane], w7 = wr[448 + lane];

    float acc = dot4_(w0, h4[lane])       + dot4_(w1, h4[ 64 + lane])
              + dot4_(w2, h4[128 + lane]) + dot4_(w3, h4[192 + lane])
              + dot4_(w4, h4[256 + lane]) + dot4_(w5, h4[320 + lane])
              + dot4_(w6, h4[384 + lane]) + dot4_(w7, h4[448 + lane]);
    #pragma unroll
    for (int off = 32; off; off >>= 1) acc += __shfl_down(acc, off);
    if (lane == 0) gates[row] = acc + bih[grow] + bhh[grow];
}

// K3: gates -> h2 (redundant per block, cheap VALU) -> fc row.
// 350 blocks x 256 thr.
__global__ __launch_bounds__(256) void k3_fc(
    const float* __restrict__ gates, const float* __restrict__ fcw,
    const float* __restrict__ fcb, float* __restrict__ out)
{
    __shared__ __align__(16) float h2s[HIDDEN];
    __shared__ float part[4];
    const int tid = threadIdx.x, wave = tid >> 6, lane = tid & 63;
    const int r = blockIdx.x;

    #pragma unroll
    for (int it = 0; it < HIDDEN / 256; ++it) {
        const int j = it * 256 + tid;
        float gi = gates[j];
        float gg = gates[HIDDEN + j];
        float go = gates[2 * HIDDEN + j];
        float c = sigmoidf_(gi) * tanhf(gg);
        h2s[j] = sigmoidf_(go) * tanhf(c);
    }
    __syncthreads();

    const float4* wr = (const float4*)(fcw + (size_t)r * HIDDEN);
    const float4* h4 = (const float4*)h2s;
    const int base = wave * 128;              // 512 float4 / 4 waves
    float acc = dot4_(wr[base + lane], h4[base + lane])
              + dot4_(wr[base + 64 + lane], h4[base + 64 + lane]);
    #pragma unroll
    for (int off = 32; off; off >>= 1) acc += __shfl_down(acc, off);
    if (lane == 0) part[wave] = acc;
    __syncthreads();
    if (tid == 0) out[r] = part[0] + part[1] + part[2] + part[3] + fcb[r];
}

extern "C" void kernel_launch(void* const* d_in, const int* in_sizes, int n_in,
                              void* d_out, int out_size, void* d_ws, size_t ws_size,
                              hipStream_t stream) {
    const float* x     = (const float*)d_in[0];
    const float* W_ih0 = (const float*)d_in[1];
    // d_in[2] = W_hh0 : unused (h0 == 0)
    const float* b_ih0 = (const float*)d_in[3];
    const float* b_hh0 = (const float*)d_in[4];
    const float* W_ih1 = (const float*)d_in[5];
    // d_in[6] = W_hh1 : unused (h == 0 for cell 2 as well)
    const float* b_ih1 = (const float*)d_in[7];
    const float* b_hh1 = (const float*)d_in[8];
    const float* fc_w  = (const float*)d_in[9];
    const float* fc_b  = (const float*)d_in[10];

    float* h1    = (float*)d_ws;            // 2048 floats
    float* gates = (float*)d_ws + HIDDEN;   // 6144 floats

    k1_feat_lstm0<<<512, 768, 0, stream>>>(x, W_ih0, b_ih0, b_hh0, h1);
    k2_rows<<<6144 / 4, 256, 0, stream>>>(W_ih1, b_ih1, b_hh1, h1, gates);
    k3_fc<<<IN_F, 256, 0, stream>>>(gates, fc_w, fc_b, (float*)d_out);
}

// Round 12
// 20.551 us; speedup vs baseline: 1.8555x; 1.2465x over previous
//
#include <hip/hip_runtime.h>
#include <math.h>

#define HIDDEN 2048
#define IN_F 350

typedef float vf2 __attribute__((ext_vector_type(2)));
typedef float vf4 __attribute__((ext_vector_type(4)));

__device__ __forceinline__ float sigmoidf_(float v) { return 1.0f / (1.0f + expf(-v)); }
__device__ __forceinline__ float dot4v_(vf4 a, vf4 b) {
    return a.x*b.x + a.y*b.y + a.z*b.z + a.w*b.w;
}

// K1: feat + LSTM layer 0 (h=c=0 => f-gate dead, W_hh unused).
// 2048 blocks x 192 thr: block = hidden unit, wave = gate (i,g,o). K=350, float2.
// Weight row loaded nontemporal (read-once stream).
__global__ __launch_bounds__(192) void k1_feat_lstm0(
    const float* __restrict__ x, const float* __restrict__ Wih,
    const float* __restrict__ bih, const float* __restrict__ bhh,
    float* __restrict__ h1)
{
    __shared__ __align__(16) float feat[IN_F];
    __shared__ float hx[84];     // hands, contiguous copy of x[182..265]
    __shared__ float sc[12];     // 4 source points (8) + dl/dr (4)
    __shared__ float ext[4];     // wl, hl, wr, hr
    __shared__ float gd[3];
    const int tid = threadIdx.x, wave = tid >> 6, lane = tid & 63;
    const int j = blockIdx.x;

    if (tid < 84) hx[tid] = x[182 + tid];
    else if (tid < 92) {
        int t = tid - 84;
        int p = t >> 1;                                   // body,face,left,right
        int base = (p == 0) ? 0 : (p == 1) ? 106 : (p == 2) ? 200 : 242;
        sc[t] = x[base + (t & 1)];
    }
    __syncthreads();
    if (tid < 4) {                                        // extrema: (hand, coord)
        const int h = tid >> 1, c = tid & 1;
        float m = hx[h*42 + c], M = m;
        #pragma unroll
        for (int jj = 1; jj < 21; ++jj) {
            float v = hx[h*42 + 2*jj + c];
            m = fminf(m, v); M = fmaxf(M, v);
        }
        ext[tid] = M - m;
    }
    __syncthreads();
    if (tid < 4) {
        const int h = tid >> 1;
        bool ok = (ext[2*h] != 0.0f) && (ext[2*h + 1] != 0.0f);
        sc[8 + tid] = ok ? ext[tid] : 1.0f;
    }
    __syncthreads();
    if (tid < 133) {
        const float sbx = sc[0], sby = sc[1], sfx = sc[2], sfy = sc[3];
        const float slx = sc[4], sly = sc[5], srx = sc[6], sry = sc[7];
        const float dlx = sc[8], dly = sc[9], drx = sc[10], dry = sc[11];
        const int k = tid;
        float vx = x[2*k], vy = x[2*k + 1];
        if (k < 17) {                 // body
            feat[2*k]   = vx - sbx;  feat[2*k+1] = vy - sby;
        } else if (k < 23) {          // feet
            feat[2*k]   = vx;        feat[2*k+1] = vy;
        } else if (k < 91) {          // face
            feat[2*k]   = vx - sfx;  feat[2*k+1] = vy - sfy;
        } else if (k < 112) {         // left hand + chin2l
            int jj = k - 91;
            feat[182 + 2*jj] = (vx - slx) / dlx;  feat[183 + 2*jj] = (vy - sly) / dly;
            feat[266 + 2*jj] = vx - sbx;          feat[267 + 2*jj] = vy - sby;
        } else {                      // right hand + chin2r
            int jj = k - 112;
            feat[224 + 2*jj] = (vx - srx) / drx;  feat[225 + 2*jj] = (vy - sry) / dry;
            feat[308 + 2*jj] = vx - sbx;          feat[309 + 2*jj] = vy - sby;
        }
    }
    __syncthreads();

    // gate dot: row = {0,2,3}[wave]*H + j, 350 floats = 175 vf2 (rows 8B-aligned)
    const int grow = ((wave == 0) ? 0 : (wave == 1) ? 2 : 3) * HIDDEN + j;
    const vf2* wr = (const vf2*)(Wih + (size_t)grow * IN_F);
    const vf2* f2 = (const vf2*)feat;
    const bool has2 = (128 + lane) < 175;
    vf2 zero2 = {0.f, 0.f};
    vf2 w0 = __builtin_nontemporal_load(wr + lane);
    vf2 w1 = __builtin_nontemporal_load(wr + 64 + lane);
    vf2 w2 = has2 ? __builtin_nontemporal_load(wr + 128 + lane) : zero2;
    vf2 f0 = f2[lane];
    vf2 f1 = f2[64 + lane];
    vf2 fx = has2 ? f2[128 + lane] : zero2;
    float acc = w0.x*f0.x + w0.y*f0.y + w1.x*f1.x + w1.y*f1.y + w2.x*fx.x + w2.y*fx.y;
    #pragma unroll
    for (int off = 32; off; off >>= 1) acc += __shfl_down(acc, off);
    if (lane == 0) gd[wave] = acc + bih[grow] + bhh[grow];
    __syncthreads();
    if (tid == 0) {
        float c = sigmoidf_(gd[0]) * tanhf(gd[1]);
        h1[j] = sigmoidf_(gd[2]) * tanhf(c);
    }
}

// K2: LSTM layer 1 (h=c=0 again). 2048 blocks x 192 thr, block=unit, wave=gate.
// K=2048: 8 vf4/lane, ALL loads hoisted; weights nontemporal (read-once),
// h1 via normal loads (8 KB, L1/L2-resident after first touch).
__global__ __launch_bounds__(192) void k2_lstm1(
    const float* __restrict__ Wih, const float* __restrict__ bih,
    const float* __restrict__ bhh, const float* __restrict__ h1,
    float* __restrict__ h2)
{
    __shared__ float gd[3];
    const int tid = threadIdx.x, wave = tid >> 6, lane = tid & 63;
    const int j = blockIdx.x;
    const int grow = ((wave == 0) ? 0 : (wave == 1) ? 2 : 3) * HIDDEN + j;
    const vf4* wr = (const vf4*)(Wih + (size_t)grow * HIDDEN);
    const vf4* h4 = (const vf4*)h1;

    vf4 wv0 = __builtin_nontemporal_load(wr + lane);
    vf4 wv1 = __builtin_nontemporal_load(wr +  64 + lane);
    vf4 wv2 = __builtin_nontemporal_load(wr + 128 + lane);
    vf4 wv3 = __builtin_nontemporal_load(wr + 192 + lane);
    vf4 wv4 = __builtin_nontemporal_load(wr + 256 + lane);
    vf4 wv5 = __builtin_nontemporal_load(wr + 320 + lane);
    vf4 wv6 = __builtin_nontemporal_load(wr + 384 + lane);
    vf4 wv7 = __builtin_nontemporal_load(wr + 448 + lane);
    vf4 hv0 = h4[lane];
    vf4 hv1 = h4[ 64 + lane];
    vf4 hv2 = h4[128 + lane];
    vf4 hv3 = h4[192 + lane];
    vf4 hv4 = h4[256 + lane];
    vf4 hv5 = h4[320 + lane];
    vf4 hv6 = h4[384 + lane];
    vf4 hv7 = h4[448 + lane];

    float acc = dot4v_(wv0, hv0) + dot4v_(wv1, hv1) + dot4v_(wv2, hv2) + dot4v_(wv3, hv3)
              + dot4v_(wv4, hv4) + dot4v_(wv5, hv5) + dot4v_(wv6, hv6) + dot4v_(wv7, hv7);
    #pragma unroll
    for (int off = 32; off; off >>= 1) acc += __shfl_down(acc, off);
    if (lane == 0) gd[wave] = acc + bih[grow] + bhh[grow];
    __syncthreads();
    if (tid == 0) {
        float c = sigmoidf_(gd[0]) * tanhf(gd[1]);
        h2[j] = sigmoidf_(gd[2]) * tanhf(c);
    }
}

// K3: out[r] = fc_w[r,:] . h2 + fc_b[r]. 350 blocks x 256 thr (4 waves, K-split).
// fc row nontemporal (read-once).
__global__ __launch_bounds__(256) void k3_fc(
    const float* __restrict__ h2, const float* __restrict__ W,
    const float* __restrict__ b, float* __restrict__ out)
{
    __shared__ float part[4];
    const int tid = threadIdx.x, wave = tid >> 6, lane = tid & 63;
    const int r = blockIdx.x;
    const vf4* wr = (const vf4*)(W + (size_t)r * HIDDEN);
    const vf4* h4 = (const vf4*)h2;
    const int base = wave * 128;              // 512 vf4 / 4 waves
    vf4 w0 = __builtin_nontemporal_load(wr + base + lane);
    vf4 w1 = __builtin_nontemporal_load(wr + base + 64 + lane);
    vf4 v0 = h4[base + lane], v1 = h4[base + 64 + lane];
    float acc = dot4v_(w0, v0) + dot4v_(w1, v1);
    #pragma unroll
    for (int off = 32; off; off >>= 1) acc += __shfl_down(acc, off);
    if (lane == 0) part[wave] = acc;
    __syncthreads();
    if (tid == 0) out[r] = part[0] + part[1] + part[2] + part[3] + b[r];
}

extern "C" void kernel_launch(void* const* d_in, const int* in_sizes, int n_in,
                              void* d_out, int out_size, void* d_ws, size_t ws_size,
                              hipStream_t stream) {
    const float* x     = (const float*)d_in[0];
    const float* W_ih0 = (const float*)d_in[1];
    // d_in[2] = W_hh0 : unused (h0 == 0)
    const float* b_ih0 = (const float*)d_in[3];
    const float* b_hh0 = (const float*)d_in[4];
    const float* W_ih1 = (const float*)d_in[5];
    // d_in[6] = W_hh1 : unused (h == 0 for cell 2 as well)
    const float* b_ih1 = (const float*)d_in[7];
    const float* b_hh1 = (const float*)d_in[8];
    const float* fc_w  = (const float*)d_in[9];
    const float* fc_b  = (const float*)d_in[10];

    float* h1 = (float*)d_ws;            // 2048 floats
    float* h2 = (float*)d_ws + HIDDEN;   // 2048 floats

    k1_feat_lstm0<<<HIDDEN, 192, 0, stream>>>(x, W_ih0, b_ih0, b_hh0, h1);
    k2_lstm1<<<HIDDEN, 192, 0, stream>>>(W_ih1, b_ih1, b_hh1, h1, h2);
    k3_fc<<<IN_F, 256, 0, stream>>>(h2, fc_w, fc_b, (float*)d_out);
}

// Round 13
// 20.472 us; speedup vs baseline: 1.8627x; 1.0039x over previous
//
#include <hip/hip_runtime.h>
#include <math.h>

#define HIDDEN 2048
#define IN_F 350

typedef float vf2 __attribute__((ext_vector_type(2)));
typedef float vf4 __attribute__((ext_vector_type(4)));

__device__ __forceinline__ float sigmoidf_(float v) { return 1.0f / (1.0f + expf(-v)); }
__device__ __forceinline__ float dot4v_(vf4 a, vf4 b) {
    return a.x*b.x + a.y*b.y + a.z*b.z + a.w*b.w;
}

// K1: feat + LSTM layer 0 (h=c=0 => f-gate dead, W_hh unused).
// 2048 blocks x 192 thr: block = hidden unit, wave = gate (i,g,o).
// Weight-row (nt) + bias loads issued at t0, BEFORE the feat LDS chain, so the
// 8.6 MB stream overlaps the feat latency instead of serializing after it.
__global__ __launch_bounds__(192) void k1_feat_lstm0(
    const float* __restrict__ x, const float* __restrict__ Wih,
    const float* __restrict__ bih, const float* __restrict__ bhh,
    float* __restrict__ h1)
{
    __shared__ __align__(16) float feat[IN_F];
    __shared__ float hx[84];     // hands, contiguous copy of x[182..265]
    __shared__ float sc[12];     // 4 source points (8) + dl/dr (4)
    __shared__ float ext[4];     // wl, hl, wr, hr
    __shared__ float gd[3];
    const int tid = threadIdx.x, wave = tid >> 6, lane = tid & 63;
    const int j = blockIdx.x;

    // ---- t0: issue weight + bias loads (no dependencies) ----
    const int grow = ((wave == 0) ? 0 : (wave == 1) ? 2 : 3) * HIDDEN + j;
    const vf2* wr = (const vf2*)(Wih + (size_t)grow * IN_F);
    const bool has2 = (128 + lane) < 175;                 // 350 floats = 175 vf2
    vf2 zero2 = {0.f, 0.f};
    vf2 w0 = __builtin_nontemporal_load(wr + lane);
    vf2 w1 = __builtin_nontemporal_load(wr + 64 + lane);
    vf2 w2 = has2 ? __builtin_nontemporal_load(wr + 128 + lane) : zero2;
    const float bsum = bih[grow] + bhh[grow];

    // ---- feat chain (overlaps the in-flight weight stream) ----
    if (tid < 84) hx[tid] = x[182 + tid];
    else if (tid < 92) {
        int t = tid - 84;
        int p = t >> 1;                                   // body,face,left,right
        int base = (p == 0) ? 0 : (p == 1) ? 106 : (p == 2) ? 200 : 242;
        sc[t] = x[base + (t & 1)];
    }
    __syncthreads();
    if (tid < 4) {                                        // extrema: (hand, coord)
        const int h = tid >> 1, c = tid & 1;
        float m = hx[h*42 + c], M = m;
        #pragma unroll
        for (int jj = 1; jj < 21; ++jj) {
            float v = hx[h*42 + 2*jj + c];
            m = fminf(m, v); M = fmaxf(M, v);
        }
        ext[tid] = M - m;
    }
    __syncthreads();
    if (tid < 4) {
        const int h = tid >> 1;
        bool ok = (ext[2*h] != 0.0f) && (ext[2*h + 1] != 0.0f);
        sc[8 + tid] = ok ? ext[tid] : 1.0f;
    }
    __syncthreads();
    if (tid < 133) {
        const float sbx = sc[0], sby = sc[1], sfx = sc[2], sfy = sc[3];
        const float slx = sc[4], sly = sc[5], srx = sc[6], sry = sc[7];
        const float dlx = sc[8], dly = sc[9], drx = sc[10], dry = sc[11];
        const int k = tid;
        float vx = x[2*k], vy = x[2*k + 1];
        if (k < 17) {                 // body
            feat[2*k]   = vx - sbx;  feat[2*k+1] = vy - sby;
        } else if (k < 23) {          // feet
            feat[2*k]   = vx;        feat[2*k+1] = vy;
        } else if (k < 91) {          // face
            feat[2*k]   = vx - sfx;  feat[2*k+1] = vy - sfy;
        } else if (k < 112) {         // left hand + chin2l
            int jj = k - 91;
            feat[182 + 2*jj] = (vx - slx) / dlx;  feat[183 + 2*jj] = (vy - sly) / dly;
            feat[266 + 2*jj] = vx - sbx;          feat[267 + 2*jj] = vy - sby;
        } else {                      // right hand + chin2r
            int jj = k - 112;
            feat[224 + 2*jj] = (vx - srx) / drx;  feat[225 + 2*jj] = (vy - sry) / dry;
            feat[308 + 2*jj] = vx - sbx;          feat[309 + 2*jj] = vy - sby;
        }
    }
    __syncthreads();

    // ---- gate dot (weights long since landed) ----
    const vf2* f2 = (const vf2*)feat;
    vf2 f0 = f2[lane];
    vf2 f1 = f2[64 + lane];
    vf2 fx = has2 ? f2[128 + lane] : zero2;
    float acc = w0.x*f0.x + w0.y*f0.y + w1.x*f1.x + w1.y*f1.y + w2.x*fx.x + w2.y*fx.y;
    #pragma unroll
    for (int off = 32; off; off >>= 1) acc += __shfl_down(acc, off);
    if (lane == 0) gd[wave] = acc + bsum;
    __syncthreads();
    if (tid == 0) {
        float c = sigmoidf_(gd[0]) * tanhf(gd[1]);
        h1[j] = sigmoidf_(gd[2]) * tanhf(c);
    }
}

// K2: LSTM layer 1 (h=c=0 again). 2048 blocks x 192 thr, block=unit, wave=gate.
// K=2048: 8 vf4/lane, ALL loads hoisted; weights nontemporal (read-once),
// h1 via normal loads (8 KB, L1/L2-resident after first touch).
__global__ __launch_bounds__(192) void k2_lstm1(
    const float* __restrict__ Wih, const float* __restrict__ bih,
    const float* __restrict__ bhh, const float* __restrict__ h1,
    float* __restrict__ h2)
{
    __shared__ float gd[3];
    const int tid = threadIdx.x, wave = tid >> 6, lane = tid & 63;
    const int j = blockIdx.x;
    const int grow = ((wave == 0) ? 0 : (wave == 1) ? 2 : 3) * HIDDEN + j;
    const vf4* wr = (const vf4*)(Wih + (size_t)grow * HIDDEN);
    const vf4* h4 = (const vf4*)h1;

    vf4 wv0 = __builtin_nontemporal_load(wr + lane);
    vf4 wv1 = __builtin_nontemporal_load(wr +  64 + lane);
    vf4 wv2 = __builtin_nontemporal_load(wr + 128 + lane);
    vf4 wv3 = __builtin_nontemporal_load(wr + 192 + lane);
    vf4 wv4 = __builtin_nontemporal_load(wr + 256 + lane);
    vf4 wv5 = __builtin_nontemporal_load(wr + 320 + lane);
    vf4 wv6 = __builtin_nontemporal_load(wr + 384 + lane);
    vf4 wv7 = __builtin_nontemporal_load(wr + 448 + lane);
    vf4 hv0 = h4[lane];
    vf4 hv1 = h4[ 64 + lane];
    vf4 hv2 = h4[128 + lane];
    vf4 hv3 = h4[192 + lane];
    vf4 hv4 = h4[256 + lane];
    vf4 hv5 = h4[320 + lane];
    vf4 hv6 = h4[384 + lane];
    vf4 hv7 = h4[448 + lane];

    float acc = dot4v_(wv0, hv0) + dot4v_(wv1, hv1) + dot4v_(wv2, hv2) + dot4v_(wv3, hv3)
              + dot4v_(wv4, hv4) + dot4v_(wv5, hv5) + dot4v_(wv6, hv6) + dot4v_(wv7, hv7);
    #pragma unroll
    for (int off = 32; off; off >>= 1) acc += __shfl_down(acc, off);
    if (lane == 0) gd[wave] = acc + bih[grow] + bhh[grow];
    __syncthreads();
    if (tid == 0) {
        float c = sigmoidf_(gd[0]) * tanhf(gd[1]);
        h2[j] = sigmoidf_(gd[2]) * tanhf(c);
    }
}

// K3: out[r] = fc_w[r,:] . h2 + fc_b[r]. 350 blocks x 256 thr (4 waves, K-split).
// fc row nontemporal (read-once).
__global__ __launch_bounds__(256) void k3_fc(
    const float* __restrict__ h2, const float* __restrict__ W,
    const float* __restrict__ b, float* __restrict__ out)
{
    __shared__ float part[4];
    const int tid = threadIdx.x, wave = tid >> 6, lane = tid & 63;
    const int r = blockIdx.x;
    const vf4* wr = (const vf4*)(W + (size_t)r * HIDDEN);
    const vf4* h4 = (const vf4*)h2;
    const int base = wave * 128;              // 512 vf4 / 4 waves
    vf4 w0 = __builtin_nontemporal_load(wr + base + lane);
    vf4 w1 = __builtin_nontemporal_load(wr + base + 64 + lane);
    vf4 v0 = h4[base + lane], v1 = h4[base + 64 + lane];
    float acc = dot4v_(w0, v0) + dot4v_(w1, v1);
    #pragma unroll
    for (int off = 32; off; off >>= 1) acc += __shfl_down(acc, off);
    if (lane == 0) part[wave] = acc;
    __syncthreads();
    if (tid == 0) out[r] = part[0] + part[1] + part[2] + part[3] + b[r];
}

extern "C" void kernel_launch(void* const* d_in, const int* in_sizes, int n_in,
                              void* d_out, int out_size, void* d_ws, size_t ws_size,
                              hipStream_t stream) {
    const float* x     = (const float*)d_in[0];
    const float* W_ih0 = (const float*)d_in[1];
    // d_in[2] = W_hh0 : unused (h0 == 0)
    const float* b_ih0 = (const float*)d_in[3];
    const float* b_hh0 = (const float*)d_in[4];
    const float* W_ih1 = (const float*)d_in[5];
    // d_in[6] = W_hh1 : unused (h == 0 for cell 2 as well)
    const float* b_ih1 = (const float*)d_in[7];
    const float* b_hh1 = (const float*)d_in[8];
    const float* fc_w  = (const float*)d_in[9];
    const float* fc_b  = (const float*)d_in[10];

    float* h1 = (float*)d_ws;            // 2048 floats
    float* h2 = (float*)d_ws + HIDDEN;   // 2048 floats

    k1_feat_lstm0<<<HIDDEN, 192, 0, stream>>>(x, W_ih0, b_ih0, b_hh0, h1);
    k2_lstm1<<<HIDDEN, 192, 0, stream>>>(W_ih1, b_ih1, b_hh1, h1, h2);
    k3_fc<<<IN_F, 256, 0, stream>>>(h2, fc_w, fc_b, (float*)d_out);
}